// Round 1
// baseline (153.609 us; speedup 1.0000x reference)
//
#include <hip/hip_runtime.h>

// Problem constants
#define BATCH  4
#define SEQL   2048
#define DMODEL 1024
#define NST    16
#define CT     64            // chunk length T
#define NCH    (SEQL / CT)   // 32 chunks

// ws layout (float offsets)
#define WS_P     0           // P[sigma][m]   = (A^(T-1-sigma) B)[m]      : CT*16
#define WS_W     1024        // W[tau][m]     = (B^T A^(tau+1))[m]        : CT*16
#define WS_KV    2048        // kvext[127], kvext[63+d] = B^T A^d B, 0 for d<0 (pad to 128)
#define WS_APOW  2176        // Apow[m][k]    = (A^CT)[m][k]              : 256
#define WS_HIN   4096        // hin[b][j][d][m] = s_{j-1}                 : B*NCH*D*16

// ---------------------------------------------------------------------------
// Setup: block delta (0..64) computes A^delta in fp64 via binary powering,
// then emits its slice of the tables. Trivial cost (~1 us), runs every call.
// ---------------------------------------------------------------------------
__global__ __launch_bounds__(256) void setup_tables(const float* __restrict__ A,
                                                    const float* __restrict__ Bv,
                                                    float* __restrict__ ws) {
    __shared__ double buf0[256], buf1[256], buf2[256], buf3[256];
    __shared__ double bd[16], vtmp[16];
    double* S  = buf0;
    double* R  = buf1;
    double* Ta = buf2;
    double* Tb = buf3;
    const int t  = threadIdx.x;
    const int i  = t >> 4;
    const int kk = t & 15;
    const int delta = blockIdx.x;   // 0..64

    S[t] = (double)A[t];
    R[t] = (i == kk) ? 1.0 : 0.0;
    if (t < 16) bd[t] = (double)Bv[t];
    __syncthreads();

    for (int sb = 0; sb < 7; ++sb) {
        if ((delta >> sb) & 1) {
            double acc = 0.0;
            #pragma unroll
            for (int l = 0; l < 16; ++l) acc += R[i * 16 + l] * S[l * 16 + kk];
            Ta[t] = acc;
            __syncthreads();
            double* tmp = R; R = Ta; Ta = tmp;
        }
        if (sb < 6) {
            double acc = 0.0;
            #pragma unroll
            for (int l = 0; l < 16; ++l) acc += S[i * 16 + l] * S[l * 16 + kk];
            Tb[t] = acc;
            __syncthreads();
            double* tmp = S; S = Tb; Tb = tmp;
        }
    }
    // R now holds A^delta (fp64)

    if (delta < CT) {
        if (t < 16) {   // m = t : P[CT-1-delta][m] = (A^delta B)[m]
            double acc = 0.0;
            #pragma unroll
            for (int k = 0; k < 16; ++k) acc += R[t * 16 + k] * bd[k];
            ws[WS_P + (CT - 1 - delta) * 16 + t] = (float)acc;
            vtmp[t] = acc;
        }
        __syncthreads();
        if (t == 0) {   // k_delta = B^T A^delta B
            double kd = 0.0;
            for (int m = 0; m < 16; ++m) kd += bd[m] * vtmp[m];
            ws[WS_KV + 63 + delta] = (float)kd;
        }
    }
    if (delta >= 1 && t < 16) {   // W[delta-1][m] = sum_n B[n] (A^delta)[n][m]
        double acc = 0.0;
        #pragma unroll
        for (int n = 0; n < 16; ++n) acc += bd[n] * R[n * 16 + t];
        ws[WS_W + (delta - 1) * 16 + t] = (float)acc;
    }
    if (delta == CT) ws[WS_APOW + t] = (float)R[t];   // A^T power matrix
    if (delta == 0 && t < 63) ws[WS_KV + t] = 0.0f;   // zero-pad negative lags
}

// ---------------------------------------------------------------------------
// K1: per (b, chunk j, channel d): c_j[m] = sum_sigma P[sigma][m] * x[sigma]
// Thread = channel (fully coalesced x reads). c written to d_out scratch.
// ---------------------------------------------------------------------------
__global__ __launch_bounds__(256) void k1_chunkstate(const float* __restrict__ x,
                                                     const float* __restrict__ ws,
                                                     float* __restrict__ cbuf) {
    const int blk  = blockIdx.x;          // 512 blocks
    const int b    = blk >> 7;            // 4
    const int j    = (blk >> 2) & 31;     // 32
    const int dblk = blk & 3;             // 4
    const int d    = dblk * 256 + threadIdx.x;

    const float* P = ws + WS_P;           // wave-uniform reads -> s_load
    float c[16];
    #pragma unroll
    for (int m = 0; m < 16; ++m) c[m] = 0.0f;

    const float* xp = x + ((size_t)(b * SEQL + j * CT)) * DMODEL + d;
    #pragma unroll
    for (int s = 0; s < CT; ++s) {
        float xv = xp[(size_t)s * DMODEL];
        #pragma unroll
        for (int m = 0; m < 16; ++m) c[m] = fmaf(P[s * 16 + m], xv, c[m]);
    }

    float4* outp = (float4*)(cbuf + (((size_t)(b * NCH + j) * DMODEL) + d) * 16);
    #pragma unroll
    for (int q = 0; q < 4; ++q)
        outp[q] = make_float4(c[4 * q], c[4 * q + 1], c[4 * q + 2], c[4 * q + 3]);
}

// ---------------------------------------------------------------------------
// K2: carry scan over chunks. Thread = (channel, state component m).
// s_j = Apow * s_{j-1} + c_j ; h_in_j = s_{j-1} written to ws.
// 16-lane groups exchange state via __shfl (no barriers).
// ---------------------------------------------------------------------------
__global__ __launch_bounds__(256) void k2_carry(const float* __restrict__ cbuf,
                                                float* __restrict__ ws) {
    const int blk = blockIdx.x;           // 256 blocks
    const int b   = blk >> 6;             // 4
    const int d0  = (blk & 63) * 16;
    const int t   = threadIdx.x;
    const int m   = t & 15;
    const int ch  = t >> 4;               // 0..15 in block
    const int d   = d0 + ch;
    const int laneBase = t & 48;          // 16-lane group base within wave

    float Arow[16];
    #pragma unroll
    for (int k = 0; k < 16; ++k) Arow[k] = ws[WS_APOW + m * 16 + k];

    float* hin = ws + WS_HIN;
    float s = 0.0f;
    for (int j = 0; j < NCH; ++j) {
        const size_t base = (((size_t)(b * NCH + j) * DMODEL) + d) * 16 + m;
        hin[base] = s;                    // h_in for chunk j = s_{j-1}
        float acc = cbuf[base];           // c_j[m]
        #pragma unroll
        for (int k = 0; k < 16; ++k)
            acc = fmaf(Arow[k], __shfl(s, laneBase + k, 64), acc);
        s = acc;
    }
}

// ---------------------------------------------------------------------------
// K3: outputs. Thread = channel, one chunk per block.
// y[tau] = W[tau].h_in + sum_{sigma<=tau} k[tau-sigma] x[sigma]
// Triangle tiled in 4 tau-tiles of 16 (zero-padded kvext handles diagonal).
// ---------------------------------------------------------------------------
__global__ __launch_bounds__(256) void k3_output(const float* __restrict__ x,
                                                 const float* __restrict__ ws,
                                                 float* __restrict__ y) {
    const int blk  = blockIdx.x;          // 512 blocks (same mapping as K1)
    const int b    = blk >> 7;
    const int j    = (blk >> 2) & 31;
    const int dblk = blk & 3;
    const int d    = dblk * 256 + threadIdx.x;

    const float* W  = ws + WS_W;
    const float* kv = ws + WS_KV;         // kvext: index 63 + lag
    const float* hinp = ws + WS_HIN + (((size_t)(b * NCH + j) * DMODEL) + d) * 16;

    float h[16];
    #pragma unroll
    for (int q = 0; q < 4; ++q) {
        float4 v = ((const float4*)hinp)[q];
        h[4 * q] = v.x; h[4 * q + 1] = v.y; h[4 * q + 2] = v.z; h[4 * q + 3] = v.w;
    }

    float yv[CT];
    #pragma unroll
    for (int ta = 0; ta < CT; ++ta) {     // correction: W[tau] . h_in
        float acc = 0.0f;
        #pragma unroll
        for (int m = 0; m < 16; ++m) acc = fmaf(W[ta * 16 + m], h[m], acc);
        yv[ta] = acc;
    }

    const float* xp = x + ((size_t)(b * SEQL + j * CT)) * DMODEL + d;
    #pragma unroll
    for (int tt = 0; tt < 4; ++tt) {
        const int lim = 16 * tt + 16;
        for (int s = 0; s < lim; ++s) {   // dynamic loop; kvext reads are uniform
            float xv = xp[(size_t)s * DMODEL];
            #pragma unroll
            for (int i = 0; i < 16; ++i)
                yv[tt * 16 + i] = fmaf(kv[63 + tt * 16 + i - s], xv, yv[tt * 16 + i]);
        }
    }

    float* yp = y + ((size_t)(b * SEQL + j * CT)) * DMODEL + d;
    #pragma unroll
    for (int ta = 0; ta < CT; ++ta) yp[(size_t)ta * DMODEL] = yv[ta];
}

// ---------------------------------------------------------------------------
extern "C" void kernel_launch(void* const* d_in, const int* in_sizes, int n_in,
                              void* d_out, int out_size, void* d_ws, size_t ws_size,
                              hipStream_t stream) {
    (void)in_sizes; (void)n_in; (void)out_size; (void)ws_size;
    const float* x  = (const float*)d_in[0];
    const float* A  = (const float*)d_in[1];
    const float* Bv = (const float*)d_in[2];
    float* out = (float*)d_out;
    float* ws  = (float*)d_ws;

    // c_j scratch lives in d_out (overwritten by K3 afterwards); h_in + tables in ws.
    setup_tables<<<65, 256, 0, stream>>>(A, Bv, ws);
    k1_chunkstate<<<512, 256, 0, stream>>>(x, ws, out);
    k2_carry<<<256, 256, 0, stream>>>(out, ws);
    k3_output<<<512, 256, 0, stream>>>(x, ws, out);
}